// Round 14
// baseline (198.519 us; speedup 1.0000x reference)
//
#include <hip/hip_runtime.h>
#include <hip/hip_fp16.h>
#include <math.h>

#define NB 32
#define NN 512
#define DD 256

constexpr float INV_EPS   = 10.0f;
constexpr float F_TINY    = 1e-16f;
constexpr float F_NORMEPS = 1e-8f;
constexpr float MARG      = 1.0f / 512.0f;   // a = b = 1/n

typedef __attribute__((ext_vector_type(8))) short bf16x8;
typedef __attribute__((ext_vector_type(4))) float f32x4;

__device__ __forceinline__ unsigned short f2bf(float f) {
    unsigned u = __float_as_uint(f);
    u += 0x7fffu + ((u >> 16) & 1u);          // round-to-nearest-even
    return (unsigned short)(u >> 16);
}
__device__ __forceinline__ int pack2(float a, float b) {
    return (int)f2bf(a) | ((int)f2bf(b) << 16);
}
__device__ __forceinline__ float sq4(float4 v) {
    return v.x * v.x + v.y * v.y + v.z * v.z + v.w * v.w;
}

// ---------------------------------------------------------------------------
// MEGA kernel: norms + cosine GEMM + 15 Sinkhorn iterations + Q + pi/cost in
// ONE cooperative launch. 256 blocks x 512 thr, 1 block/CU.
// Block (b, o) computes its OWN 64x512 C-stripe (M=64 rows o*64.., N=512,
// K=256), so the Sinkhorn phase's E tile never leaves the CU (fragment->LDS
// sE transpose). No cross-block dependency beyond the PROVEN cp/flag
// exchange (verbatim R12). C written once (output + own-block pi reads).
// Norms: thread tt stages full y-row tt (ssB, no reduce); threads<64 stage
// full x-rows (ssA, no reduce). Swizzle/fragment formulas carried 1:1 from
// the verified R13 gemm (row stride 64 B identical; Bh just has 512 rows).
// bars/cost are pre-zeroed by hipMemsetAsync in the launcher (in-kernel
// zeroing would race with same-kernel flag use).
// ---------------------------------------------------------------------------
__global__ __launch_bounds__(512, 2) void sinkhorn_mega(
        const float* __restrict__ x, const float* __restrict__ y,
        float* __restrict__ C,
        float* __restrict__ cp0, float* __restrict__ cp1,
        float* __restrict__ pi, float* __restrict__ cost,
        int* __restrict__ bars) {
    int blk = blockIdx.x;
    int xcd = blk & 7, qq = blk >> 3;
    int o = qq & 7;                       // stripe slot within batch
    int b = ((qq >> 3) << 3) | xcd;       // batch (8 stripes share blk%8/XCD)
    int tt = threadIdx.x, w = tt >> 6, l = tt & 63;
    int q = l >> 4, low = l & 15;
    int* flags = &bars[b * 64];           // 8 per-stripe flags, one line

    __shared__ short Ah[64][32], Bh[512][32];     // 4 KB + 32 KB
    __shared__ __half sE[64][520];                // 66.5 KB (pad 8: bank-shift)
    __shared__ float sW[NN];                      // 2 KB (reused for Q)
    __shared__ float sWP[8][NN];                  // 16 KB
    __shared__ float sNx[64], sNy[512];           // 2.25 KB
    __shared__ float sPart[8];

    // ================= phase 1: stripe GEMM =================
    const float* xb = x + ((size_t)b * NN + o * 64) * DD;
    const float* yb = y + (size_t)b * NN * DD;

    f32x4 acc[4][4];
#pragma unroll
    for (int m = 0; m < 4; ++m)
#pragma unroll
        for (int nj = 0; nj < 4; ++nj) acc[m][nj] = (f32x4){0.f, 0.f, 0.f, 0.f};

    int sbase = (tt >> 1) & 3;            // row=tt chunk-swizzle selector
    float ssA = 0.0f, ssB = 0.0f;

    for (int k0 = 0; k0 < DD; k0 += 32) {
        {   // B: thread tt stages y-row tt, k0..k0+31 (8 float4)
            const float4* gy = (const float4*)(yb + (size_t)tt * DD + k0);
            float4 b0 = gy[0], b1 = gy[1], b2 = gy[2], b3 = gy[3];
            float4 b4 = gy[4], b5 = gy[5], b6 = gy[6], b7 = gy[7];
            ssB += sq4(b0) + sq4(b1) + sq4(b2) + sq4(b3)
                 + sq4(b4) + sq4(b5) + sq4(b6) + sq4(b7);
            int4 c0 = { pack2(b0.x,b0.y), pack2(b0.z,b0.w),
                        pack2(b1.x,b1.y), pack2(b1.z,b1.w) };
            int4 c1 = { pack2(b2.x,b2.y), pack2(b2.z,b2.w),
                        pack2(b3.x,b3.y), pack2(b3.z,b3.w) };
            int4 c2 = { pack2(b4.x,b4.y), pack2(b4.z,b4.w),
                        pack2(b5.x,b5.y), pack2(b5.z,b5.w) };
            int4 c3 = { pack2(b6.x,b6.y), pack2(b6.z,b6.w),
                        pack2(b7.x,b7.y), pack2(b7.z,b7.w) };
            *(int4*)&Bh[tt][(0 ^ sbase) * 8] = c0;
            *(int4*)&Bh[tt][(1 ^ sbase) * 8] = c1;
            *(int4*)&Bh[tt][(2 ^ sbase) * 8] = c2;
            *(int4*)&Bh[tt][(3 ^ sbase) * 8] = c3;
        }
        if (tt < 64) {   // A: thread tt stages x-row tt of the stripe
            const float4* gx = (const float4*)(xb + (size_t)tt * DD + k0);
            float4 a0 = gx[0], a1 = gx[1], a2 = gx[2], a3 = gx[3];
            float4 a4 = gx[4], a5 = gx[5], a6 = gx[6], a7 = gx[7];
            ssA += sq4(a0) + sq4(a1) + sq4(a2) + sq4(a3)
                 + sq4(a4) + sq4(a5) + sq4(a6) + sq4(a7);
            int4 c0 = { pack2(a0.x,a0.y), pack2(a0.z,a0.w),
                        pack2(a1.x,a1.y), pack2(a1.z,a1.w) };
            int4 c1 = { pack2(a2.x,a2.y), pack2(a2.z,a2.w),
                        pack2(a3.x,a3.y), pack2(a3.z,a3.w) };
            int4 c2 = { pack2(a4.x,a4.y), pack2(a4.z,a4.w),
                        pack2(a5.x,a5.y), pack2(a5.z,a5.w) };
            int4 c3 = { pack2(a6.x,a6.y), pack2(a6.z,a6.w),
                        pack2(a7.x,a7.y), pack2(a7.z,a7.w) };
            *(int4*)&Ah[tt][(0 ^ sbase) * 8] = c0;
            *(int4*)&Ah[tt][(1 ^ sbase) * 8] = c1;
            *(int4*)&Ah[tt][(2 ^ sbase) * 8] = c2;
            *(int4*)&Ah[tt][(3 ^ sbase) * 8] = c3;
        }
        __syncthreads();

        // wave w owns output cols w*64 .. w*64+63
        bf16x8 af[4], bf[4];
#pragma unroll
        for (int m = 0; m < 4; ++m) {
            int r = m * 16 + low;
            af[m] = *(const bf16x8*)&Ah[r][(q ^ ((r >> 1) & 3)) * 8];
        }
#pragma unroll
        for (int nj = 0; nj < 4; ++nj) {
            int r = w * 64 + nj * 16 + low;
            bf[nj] = *(const bf16x8*)&Bh[r][(q ^ ((r >> 1) & 3)) * 8];
        }
#pragma unroll
        for (int nj = 0; nj < 4; ++nj)
#pragma unroll
            for (int m = 0; m < 4; ++m)
                acc[m][nj] = __builtin_amdgcn_mfma_f32_16x16x32_bf16(
                    af[m], bf[nj], acc[m][nj], 0, 0, 0);
        __syncthreads();
    }

    // norms (no reduce needed: each thread owned its full row)
    if (tt < 64) sNx[tt] = sqrtf(ssA);
    sNy[tt] = sqrtf(ssB);
    __syncthreads();

    // epilogue: C/D layout col=lane&15, row=(lane>>4)*4+reg  [m89-corrected]
    // write C (global, output) + sE (LDS, fp16 E for phase 2)
    float* Cb = C + ((size_t)b * NN + o * 64) * NN;
#pragma unroll
    for (int m = 0; m < 4; ++m) {
#pragma unroll
        for (int nj = 0; nj < 4; ++nj) {
            int rl0 = m * 16 + q * 4;
            int cl  = w * 64 + nj * 16 + low;
            float nyc = sNy[cl];
            f32x4 a = acc[m][nj];
#pragma unroll
            for (int reg = 0; reg < 4; ++reg) {
                int rl = rl0 + reg;
                float d = 1.0f - a[reg] / fmaxf(sNx[rl] * nyc, F_NORMEPS);
                Cb[(size_t)rl * NN + cl] = d;
                sE[rl][cl] = __float2half(__expf(-INV_EPS * d));
            }
        }
    }
    __syncthreads();                      // sE complete

    // ================= phase 2: Sinkhorn (verbatim R12 protocol) =========
    // E tile from LDS: thread (w,l) owns rows w*8+i, cols 8l..8l+7
    int4 raw[8];
#pragma unroll
    for (int i = 0; i < 8; ++i)
        raw[i] = *(const int4*)&sE[w * 8 + i][8 * l];

    float A[8], Pr[8];
#pragma unroll
    for (int i = 0; i < 8; ++i) { A[i] = 1.0f; Pr[i] = 0.0f; }
    float Br = 1.0f;                      // cumulative col scaling

    float* cpr = cp0;                     // read buffer
    float* cpw = cp1;                     // iter 1 writes cp1

    for (int t = 1; t <= 15; ++t) {
        // ---- step 1: finish v_{t-1}; t==1 has v_0=1, B_0=1
        if (t == 1) {
            sW[tt] = 1.0f;
        } else {
            if (tt < 8) {
                while (__hip_atomic_load(&flags[tt], __ATOMIC_RELAXED,
                                         __HIP_MEMORY_SCOPE_AGENT) < t - 1)
                    __builtin_amdgcn_s_sleep(1);
            }
            __syncthreads();
            float sv = 0.0f;
#pragma unroll
            for (int k = 0; k < 8; ++k)
                sv += __hip_atomic_load(
                    &cpr[(size_t)(b * 8 + k) * NN + tt],
                    __ATOMIC_RELAXED, __HIP_MEMORY_SCOPE_AGENT);
            float vv = MARG / (Br * sv + F_TINY);
            Br *= vv;                      // B_{t-1}
            sW[tt] = Br * vv;              // w_m
        }
        __syncthreads();                  // sW ready

        float wr[8];
        *(float4*)&wr[0] = *(const float4*)&sW[8 * l];
        *(float4*)&wr[4] = *(const float4*)&sW[8 * l + 4];

        // ---- steps 2+3 merged (bit-identical fp order to split version)
        float p[8];
#pragma unroll
        for (int e = 0; e < 8; ++e) p[e] = 0.0f;
#pragma unroll
        for (int i = 0; i < 8; ++i) {
            const __half* hv = (const __half*)&raw[i];
            float f0 = __half2float(hv[0]), f1 = __half2float(hv[1]);
            float f2 = __half2float(hv[2]), f3 = __half2float(hv[3]);
            float f4 = __half2float(hv[4]), f5 = __half2float(hv[5]);
            float f6 = __half2float(hv[6]), f7 = __half2float(hv[7]);
            float s = 0.0f;
            s = fmaf(f0, wr[0], s); s = fmaf(f1, wr[1], s);
            s = fmaf(f2, wr[2], s); s = fmaf(f3, wr[3], s);
            s = fmaf(f4, wr[4], s); s = fmaf(f5, wr[5], s);
            s = fmaf(f6, wr[6], s); s = fmaf(f7, wr[7], s);
#pragma unroll
            for (int off = 32; off; off >>= 1) s += __shfl_xor(s, off);
            float uu = MARG / (A[i] * s + F_TINY);
            A[i] *= uu;
            if (t == 15) Pr[i] = A[i] * uu;   // P = A_15 * u_15 (all lanes)
            float ai = A[i];
            p[0] = fmaf(f0, ai, p[0]); p[1] = fmaf(f1, ai, p[1]);
            p[2] = fmaf(f2, ai, p[2]); p[3] = fmaf(f3, ai, p[3]);
            p[4] = fmaf(f4, ai, p[4]); p[5] = fmaf(f5, ai, p[5]);
            p[6] = fmaf(f6, ai, p[6]); p[7] = fmaf(f7, ai, p[7]);
        }
        *(float4*)&sWP[w][8 * l]     = make_float4(p[0], p[1], p[2], p[3]);
        *(float4*)&sWP[w][8 * l + 4] = make_float4(p[4], p[5], p[6], p[7]);
        __syncthreads();
        float cs = 0.0f;
#pragma unroll
        for (int ww = 0; ww < 8; ++ww) cs += sWP[ww][tt];
        cpw[(size_t)(b * 8 + o) * NN + tt] = cs;

        // ---- arrive: syncthreads drains vmcnt (cp stores at L2, L1 is
        //      write-through), then one flag STORE (no RMW chain).
        __syncthreads();
        if (tt == 0)
            __hip_atomic_store(&flags[o], t, __ATOMIC_RELAXED,
                               __HIP_MEMORY_SCOPE_AGENT);

        float* tmp = cpr; cpr = cpw; cpw = tmp;   // swap buffers
    }

    // ---- finish Q: wait for iter-15 flags, then full Q vector per block
    if (tt < 8) {
        while (__hip_atomic_load(&flags[tt], __ATOMIC_RELAXED,
                                 __HIP_MEMORY_SCOPE_AGENT) < 15)
            __builtin_amdgcn_s_sleep(1);
    }
    __syncthreads();
    {
        float sv = 0.0f;
#pragma unroll
        for (int k = 0; k < 8; ++k)
            sv += __hip_atomic_load(
                &cpr[(size_t)(b * 8 + k) * NN + tt],   // cp_15
                __ATOMIC_RELAXED, __HIP_MEMORY_SCOPE_AGENT);
        float vv = MARG / (Br * sv + F_TINY);           // Br = B_14
        sW[tt] = Br * vv * vv;            // Q_m = B_15 * v_15 (reuse sW)
    }
    __syncthreads();                      // Q visible block-wide

    // ================= phase 3: pi / cost (verbatim R12) =================
    float q0[8];
    *(float4*)&q0[0] = *(const float4*)&sW[4 * l];
    *(float4*)&q0[4] = *(const float4*)&sW[256 + 4 * l];
    const float* Cb2 = C + (size_t)b * NN * NN;
    float* pib = pi + (size_t)b * NN * NN;
    float csum = 0.0f;
#pragma unroll 2
    for (int i = 0; i < 8; ++i) {
        int r = o * 64 + w * 8 + i;
        float pf = Pr[i];
        const float* crow = Cb2 + (size_t)r * NN;
        float* prow = pib + (size_t)r * NN;
        float4 c0 = *(const float4*)(crow + 4 * l);
        float4 c1 = *(const float4*)(crow + 256 + 4 * l);
        float pv0 = pf * q0[0] * __expf(-INV_EPS * c0.x);
        float pv1 = pf * q0[1] * __expf(-INV_EPS * c0.y);
        float pv2 = pf * q0[2] * __expf(-INV_EPS * c0.z);
        float pv3 = pf * q0[3] * __expf(-INV_EPS * c0.w);
        float pv4 = pf * q0[4] * __expf(-INV_EPS * c1.x);
        float pv5 = pf * q0[5] * __expf(-INV_EPS * c1.y);
        float pv6 = pf * q0[6] * __expf(-INV_EPS * c1.z);
        float pv7 = pf * q0[7] * __expf(-INV_EPS * c1.w);
        *(float4*)(prow + 4 * l)       = make_float4(pv0, pv1, pv2, pv3);
        *(float4*)(prow + 256 + 4 * l) = make_float4(pv4, pv5, pv6, pv7);
        csum = fmaf(pv0, c0.x, csum); csum = fmaf(pv1, c0.y, csum);
        csum = fmaf(pv2, c0.z, csum); csum = fmaf(pv3, c0.w, csum);
        csum = fmaf(pv4, c1.x, csum); csum = fmaf(pv5, c1.y, csum);
        csum = fmaf(pv6, c1.z, csum); csum = fmaf(pv7, c1.w, csum);
    }
#pragma unroll
    for (int off = 32; off; off >>= 1) csum += __shfl_xor(csum, off);
    if (l == 0) sPart[w] = csum;
    __syncthreads();
    if (tt == 0) {
        float tot = 0.0f;
#pragma unroll
        for (int ww = 0; ww < 8; ++ww) tot += sPart[ww];
        atomicAdd(&cost[b], tot);
    }
}

// ---------------------------------------------------------------------------
extern "C" void kernel_launch(void* const* d_in, const int* in_sizes, int n_in,
                              void* d_out, int out_size, void* d_ws, size_t ws_size,
                              hipStream_t stream) {
    const float* x = (const float*)d_in[0];
    const float* y = (const float*)d_in[1];
    float* out  = (float*)d_out;
    float* cost = out;                                   // [32]
    float* pi   = out + 32;                              // [32*512*512]
    float* C    = out + 32 + (size_t)NB * NN * NN;       // [32*512*512]

    // Workspace: flags + cp double buffer.
    int* bars = (int*)d_ws;                                   // 8 KB
    float* cp0 = (float*)((char*)d_ws + 8192);                // 0.52 MB
    float* cp1 = cp0 + (size_t)NB * 8 * NN;                   // 0.52 MB

    // Pre-zero flags + cost (in-kernel zeroing would race with same-kernel
    // flag/atomic use). Both are graph-capturable stream ops.
    hipMemsetAsync(bars, 0, 8192, stream);
    hipMemsetAsync(cost, 0, NB * sizeof(float), stream);

    const float* x_p = x; const float* y_p = y; float* C_p = C;
    float* cp0_p = cp0; float* cp1_p = cp1;
    float* pi_p = pi; float* cost_p = cost; int* bars_p = bars;
    void* args[] = { &x_p, &y_p, &C_p, &cp0_p, &cp1_p,
                     &pi_p, &cost_p, &bars_p };
    hipLaunchCooperativeKernel(reinterpret_cast<void*>(sinkhorn_mega),
                               dim3(256), dim3(512), args, 0, stream);
}

// Round 15
// 172.344 us; speedup vs baseline: 1.1519x; 1.1519x over previous
//
#include <hip/hip_runtime.h>
#include <hip/hip_fp16.h>
#include <math.h>

#define NB 32
#define NN 512
#define DD 256

constexpr float INV_EPS   = 10.0f;
constexpr float F_TINY    = 1e-16f;
constexpr float F_NORMEPS = 1e-8f;
constexpr float MARG      = 1.0f / 512.0f;   // a = b = 1/n

// bars: one 256B line per batch; ints [b*64 + o] (o=0..7) hold the last
// completed iteration of stripe o of batch b (monotonic flags, no RMW).
#define BARS_N 2048

typedef __attribute__((ext_vector_type(8))) short bf16x8;
typedef __attribute__((ext_vector_type(4))) float f32x4;

__device__ __forceinline__ unsigned short f2bf(float f) {
    unsigned u = __float_as_uint(f);
    u += 0x7fffu + ((u >> 16) & 1u);          // round-to-nearest-even
    return (unsigned short)(u >> 16);
}
__device__ __forceinline__ int pack2(float a, float b) {
    return (int)f2bf(a) | ((int)f2bf(b) << 16);
}

// ---------------------------------------------------------------------------
// Fused norms + cosine GEMM:  C[b,n,m] = 1 - <x_n,y_m>/max(|x_n||y_m|,1e-8)
// Reads f32 x,y directly; staging converts f32->bf16 inline and accumulates
// row sum-of-squares across the k-loop (2 staging threads/row -> shfl_xor(1)
// partner reduce -> LDS norms for the epilogue). Writes ONLY C (f32);
// E is recomputed in sink_fused from the same C values.
// 128x128 tile, BK=32, 256 thr, XOR-swizzled LDS, 2 blocks/CU.
// Block 0 zeroes cost+bars. (Verbatim from the passing R13 build, 177.4 µs.)
// ---------------------------------------------------------------------------
__global__ __launch_bounds__(256) void gemm_cos_mfma(
        const float* __restrict__ x, const float* __restrict__ y,
        float* __restrict__ C, float* __restrict__ cost,
        int* __restrict__ bars) {
    int blk = blockIdx.x;
    int b = blk >> 4, ti = (blk >> 2) & 3, tj = blk & 3;
    if (blk == 0) {
        if (threadIdx.x < NB) cost[threadIdx.x] = 0.0f;
        for (int i = threadIdx.x; i < BARS_N; i += 256) bars[i] = 0;
    }
    __shared__ short Ah[128][32], Bh[128][32];
    __shared__ float sNx[128], sNy[128];
    const float* xb = x + ((size_t)b * NN + ti * 128) * DD;
    const float* yb = y + ((size_t)b * NN + tj * 128) * DD;
    int t = threadIdx.x, w = t >> 6, l = t & 63;
    int rw = w * 32, q = l >> 4, low = l & 15;

    f32x4 acc[2][8];
#pragma unroll
    for (int i = 0; i < 2; ++i)
#pragma unroll
        for (int j = 0; j < 8; ++j) acc[i][j] = (f32x4){0.f, 0.f, 0.f, 0.f};

    int sr = t >> 1, h = t & 1;               // staging: 2 threads/row
    int c0i = 2 * h, c1i = 2 * h + 1;         // logical 16B bf16 chunks
    int sw0 = (c0i ^ ((sr >> 1) & 3)) * 8;    // swizzled short offsets
    int sw1 = (c1i ^ ((sr >> 1) & 3)) * 8;
    float ssA = 0.0f, ssB = 0.0f;             // row sum-of-squares partials

    for (int k0 = 0; k0 < DD; k0 += 32) {
        {
            const float4* ga = (const float4*)(xb + (size_t)sr * DD + k0 + 16 * h);
            const float4* gc = (const float4*)(yb + (size_t)sr * DD + k0 + 16 * h);
            float4 a0 = ga[0], a1 = ga[1], a2 = ga[2], a3 = ga[3];
            float4 c0 = gc[0], c1 = gc[1], c2 = gc[2], c3 = gc[3];
            ssA += a0.x*a0.x + a0.y*a0.y + a0.z*a0.z + a0.w*a0.w;
            ssA += a1.x*a1.x + a1.y*a1.y + a1.z*a1.z + a1.w*a1.w;
            ssA += a2.x*a2.x + a2.y*a2.y + a2.z*a2.z + a2.w*a2.w;
            ssA += a3.x*a3.x + a3.y*a3.y + a3.z*a3.z + a3.w*a3.w;
            ssB += c0.x*c0.x + c0.y*c0.y + c0.z*c0.z + c0.w*c0.w;
            ssB += c1.x*c1.x + c1.y*c1.y + c1.z*c1.z + c1.w*c1.w;
            ssB += c2.x*c2.x + c2.y*c2.y + c2.z*c2.z + c2.w*c2.w;
            ssB += c3.x*c3.x + c3.y*c3.y + c3.z*c3.z + c3.w*c3.w;
            int4 pa0 = { pack2(a0.x,a0.y), pack2(a0.z,a0.w),
                         pack2(a1.x,a1.y), pack2(a1.z,a1.w) };
            int4 pa1 = { pack2(a2.x,a2.y), pack2(a2.z,a2.w),
                         pack2(a3.x,a3.y), pack2(a3.z,a3.w) };
            int4 pc0 = { pack2(c0.x,c0.y), pack2(c0.z,c0.w),
                         pack2(c1.x,c1.y), pack2(c1.z,c1.w) };
            int4 pc1 = { pack2(c2.x,c2.y), pack2(c2.z,c2.w),
                         pack2(c3.x,c3.y), pack2(c3.z,c3.w) };
            *(int4*)&Ah[sr][sw0] = pa0; *(int4*)&Ah[sr][sw1] = pa1;
            *(int4*)&Bh[sr][sw0] = pc0; *(int4*)&Bh[sr][sw1] = pc1;
        }
        __syncthreads();

        bf16x8 ah[2];
#pragma unroll
        for (int ti2 = 0; ti2 < 2; ++ti2) {
            int m = rw + ti2 * 16 + low;
            int pq = (q ^ ((m >> 1) & 3)) * 8;
            ah[ti2] = *(const bf16x8*)&Ah[m][pq];
        }
#pragma unroll
        for (int tj2 = 0; tj2 < 8; ++tj2) {
            int n = tj2 * 16 + low;
            int pq = (q ^ ((n >> 1) & 3)) * 8;
            bf16x8 bh = *(const bf16x8*)&Bh[n][pq];
#pragma unroll
            for (int ti2 = 0; ti2 < 2; ++ti2)
                acc[ti2][tj2] = __builtin_amdgcn_mfma_f32_16x16x32_bf16(
                    ah[ti2], bh, acc[ti2][tj2], 0, 0, 0);
        }
        __syncthreads();
    }

    // ---- finish row norms: partner thread (t^1) holds the other half
    float tA = ssA + __shfl_xor(ssA, 1);
    float tB = ssB + __shfl_xor(ssB, 1);
    if (h == 0) { sNx[sr] = sqrtf(tA); sNy[sr] = sqrtf(tB); }
    __syncthreads();

    // epilogue: C/D layout col=lane&15, row=(lane>>4)*4+reg  [m89-corrected]
    float* Cb = C + (size_t)b * NN * NN;
#pragma unroll
    for (int ti2 = 0; ti2 < 2; ++ti2) {
#pragma unroll
        for (int tj2 = 0; tj2 < 8; ++tj2) {
            int ml0 = rw + ti2 * 16 + q * 4;          // local m
            int nl  = tj2 * 16 + low;                 // local n
            int gm0 = ti * 128 + ml0;
            int gn  = tj * 128 + nl;
            float nyc = sNy[nl];
            f32x4 a = acc[ti2][tj2];
#pragma unroll
            for (int reg = 0; reg < 4; ++reg) {
                int gm = gm0 + reg;
                float d = 1.0f - a[reg] / fmaxf(sNx[ml0 + reg] * nyc, F_NORMEPS);
                Cb[(size_t)gm * NN + gn] = d;
            }
        }
    }
}

// ---------------------------------------------------------------------------
// Fully fused Sinkhorn — VERBATIM R12/R13 (passing): proven 4-sync protocol,
// 256 blocks, 64-row stripes, E-from-C in registers, merged steps 2+3
// (one conversion pass/row, bit-identical fp order), pi unroll 2.
// ---------------------------------------------------------------------------
__global__ __launch_bounds__(512, 2) void sink_fused(
        const float* __restrict__ C,
        float* __restrict__ cp0, float* __restrict__ cp1,
        float* __restrict__ pi, float* __restrict__ cost,
        int* __restrict__ bars) {
    int blk = blockIdx.x;
    int xcd = blk & 7, qq = blk >> 3;
    int o = qq & 7;                       // stripe slot within batch
    int b = ((qq >> 3) << 3) | xcd;       // batch (8 stripes share blk%8/XCD)
    int tt = threadIdx.x, w = tt >> 6, l = tt & 63;
    int* flags = &bars[b * 64];           // 8 per-stripe flags, one line

    __shared__ float sW[NN];              // w_m (later reused for Q)
    __shared__ float sWP[8][NN];          // per-wave column partials
    __shared__ float sPart[8];

    // ---- E tile: compute fp16(exp(-10*C)) from f32 C, global -> registers,
    //      resident across all 15 iterations.
    int4 raw[8];
    {
        const float* Cl = C + ((size_t)b * NN + o * 64 + w * 8) * NN + 8 * l;
#pragma unroll
        for (int i = 0; i < 8; ++i) {
            float4 c0 = *(const float4*)(Cl + (size_t)i * NN);
            float4 c1 = *(const float4*)(Cl + (size_t)i * NN + 4);
            __half h[8];
            h[0] = __float2half(__expf(-INV_EPS * c0.x));
            h[1] = __float2half(__expf(-INV_EPS * c0.y));
            h[2] = __float2half(__expf(-INV_EPS * c0.z));
            h[3] = __float2half(__expf(-INV_EPS * c0.w));
            h[4] = __float2half(__expf(-INV_EPS * c1.x));
            h[5] = __float2half(__expf(-INV_EPS * c1.y));
            h[6] = __float2half(__expf(-INV_EPS * c1.z));
            h[7] = __float2half(__expf(-INV_EPS * c1.w));
            raw[i] = *(const int4*)h;
        }
    }

    float A[8], Pr[8];
#pragma unroll
    for (int i = 0; i < 8; ++i) { A[i] = 1.0f; Pr[i] = 0.0f; }
    float Br = 1.0f;                      // cumulative col scaling

    float* cpr = cp0;                     // read buffer
    float* cpw = cp1;                     // iter 1 writes cp1

    for (int t = 1; t <= 15; ++t) {
        // ---- step 1: finish v_{t-1}; t==1 has v_0=1, B_0=1
        if (t == 1) {
            sW[tt] = 1.0f;
        } else {
            // wait: all 8 stripes have completed iteration t-1
            if (tt < 8) {
                while (__hip_atomic_load(&flags[tt], __ATOMIC_RELAXED,
                                         __HIP_MEMORY_SCOPE_AGENT) < t - 1)
                    __builtin_amdgcn_s_sleep(1);
            }
            __syncthreads();
            float sv = 0.0f;
#pragma unroll
            for (int k = 0; k < 8; ++k)
                sv += __hip_atomic_load(
                    &cpr[(size_t)(b * 8 + k) * NN + tt],
                    __ATOMIC_RELAXED, __HIP_MEMORY_SCOPE_AGENT);
            float vv = MARG / (Br * sv + F_TINY);
            Br *= vv;                      // B_{t-1}
            sW[tt] = Br * vv;              // w_m
        }
        __syncthreads();                  // sW ready

        float wr[8];
        *(float4*)&wr[0] = *(const float4*)&sW[8 * l];
        *(float4*)&wr[4] = *(const float4*)&sW[8 * l + 4];

        // ---- steps 2+3 merged: one conversion pass per row; p[e]
        //      accumulates right after A[i] is finalized (same fp order
        //      as the split version -> bit-identical results).
        float p[8];
#pragma unroll
        for (int e = 0; e < 8; ++e) p[e] = 0.0f;
#pragma unroll
        for (int i = 0; i < 8; ++i) {
            const __half* hv = (const __half*)&raw[i];
            float f0 = __half2float(hv[0]), f1 = __half2float(hv[1]);
            float f2 = __half2float(hv[2]), f3 = __half2float(hv[3]);
            float f4 = __half2float(hv[4]), f5 = __half2float(hv[5]);
            float f6 = __half2float(hv[6]), f7 = __half2float(hv[7]);
            float s = 0.0f;
            s = fmaf(f0, wr[0], s); s = fmaf(f1, wr[1], s);
            s = fmaf(f2, wr[2], s); s = fmaf(f3, wr[3], s);
            s = fmaf(f4, wr[4], s); s = fmaf(f5, wr[5], s);
            s = fmaf(f6, wr[6], s); s = fmaf(f7, wr[7], s);
#pragma unroll
            for (int off = 32; off; off >>= 1) s += __shfl_xor(s, off);
            float uu = MARG / (A[i] * s + F_TINY);
            A[i] *= uu;
            if (t == 15) Pr[i] = A[i] * uu;   // P = A_15 * u_15 (all lanes)
            float ai = A[i];
            p[0] = fmaf(f0, ai, p[0]); p[1] = fmaf(f1, ai, p[1]);
            p[2] = fmaf(f2, ai, p[2]); p[3] = fmaf(f3, ai, p[3]);
            p[4] = fmaf(f4, ai, p[4]); p[5] = fmaf(f5, ai, p[5]);
            p[6] = fmaf(f6, ai, p[6]); p[7] = fmaf(f7, ai, p[7]);
        }
        *(float4*)&sWP[w][8 * l]     = make_float4(p[0], p[1], p[2], p[3]);
        *(float4*)&sWP[w][8 * l + 4] = make_float4(p[4], p[5], p[6], p[7]);
        __syncthreads();
        float cs = 0.0f;
#pragma unroll
        for (int ww = 0; ww < 8; ++ww) cs += sWP[ww][tt];
        cpw[(size_t)(b * 8 + o) * NN + tt] = cs;

        // ---- arrive: syncthreads drains vmcnt (cp stores at L2, L1 is
        //      write-through), then one flag STORE (no RMW chain).
        __syncthreads();
        if (tt == 0)
            __hip_atomic_store(&flags[o], t, __ATOMIC_RELAXED,
                               __HIP_MEMORY_SCOPE_AGENT);

        float* tmp = cpr; cpr = cpw; cpw = tmp;   // swap buffers
    }

    // ---- finish Q: wait for iter-15 flags, then full Q vector per block
    if (tt < 8) {
        while (__hip_atomic_load(&flags[tt], __ATOMIC_RELAXED,
                                 __HIP_MEMORY_SCOPE_AGENT) < 15)
            __builtin_amdgcn_s_sleep(1);
    }
    __syncthreads();
    {
        float sv = 0.0f;
#pragma unroll
        for (int k = 0; k < 8; ++k)
            sv += __hip_atomic_load(
                &cpr[(size_t)(b * 8 + k) * NN + tt],   // cp_15
                __ATOMIC_RELAXED, __HIP_MEMORY_SCOPE_AGENT);
        float vv = MARG / (Br * sv + F_TINY);           // Br = B_14
        sW[tt] = Br * vv * vv;            // Q_m = B_15 * v_15 (reuse sW)
    }
    __syncthreads();                      // Q visible block-wide

    // ---- pi phase: identical math to verified pi_cost (f32 C, __expf)
    float q0[8];
    *(float4*)&q0[0] = *(const float4*)&sW[4 * l];
    *(float4*)&q0[4] = *(const float4*)&sW[256 + 4 * l];
    const float* Cb = C + (size_t)b * NN * NN;
    float* pib = pi + (size_t)b * NN * NN;
    float csum = 0.0f;
#pragma unroll 2
    for (int i = 0; i < 8; ++i) {
        int r = o * 64 + w * 8 + i;
        float pf = Pr[i];
        const float* crow = Cb + (size_t)r * NN;
        float* prow = pib + (size_t)r * NN;
        float4 c0 = *(const float4*)(crow + 4 * l);
        float4 c1 = *(const float4*)(crow + 256 + 4 * l);
        float pv0 = pf * q0[0] * __expf(-INV_EPS * c0.x);
        float pv1 = pf * q0[1] * __expf(-INV_EPS * c0.y);
        float pv2 = pf * q0[2] * __expf(-INV_EPS * c0.z);
        float pv3 = pf * q0[3] * __expf(-INV_EPS * c0.w);
        float pv4 = pf * q0[4] * __expf(-INV_EPS * c1.x);
        float pv5 = pf * q0[5] * __expf(-INV_EPS * c1.y);
        float pv6 = pf * q0[6] * __expf(-INV_EPS * c1.z);
        float pv7 = pf * q0[7] * __expf(-INV_EPS * c1.w);
        *(float4*)(prow + 4 * l)       = make_float4(pv0, pv1, pv2, pv3);
        *(float4*)(prow + 256 + 4 * l) = make_float4(pv4, pv5, pv6, pv7);
        csum = fmaf(pv0, c0.x, csum); csum = fmaf(pv1, c0.y, csum);
        csum = fmaf(pv2, c0.z, csum); csum = fmaf(pv3, c0.w, csum);
        csum = fmaf(pv4, c1.x, csum); csum = fmaf(pv5, c1.y, csum);
        csum = fmaf(pv6, c1.z, csum); csum = fmaf(pv7, c1.w, csum);
    }
#pragma unroll
    for (int off = 32; off; off >>= 1) csum += __shfl_xor(csum, off);
    if (l == 0) sPart[w] = csum;
    __syncthreads();
    if (tt == 0) {
        float tot = 0.0f;
#pragma unroll
        for (int ww = 0; ww < 8; ++ww) tot += sPart[ww];
        atomicAdd(&cost[b], tot);
    }
}

// ---------------------------------------------------------------------------
extern "C" void kernel_launch(void* const* d_in, const int* in_sizes, int n_in,
                              void* d_out, int out_size, void* d_ws, size_t ws_size,
                              hipStream_t stream) {
    const float* x = (const float*)d_in[0];
    const float* y = (const float*)d_in[1];
    float* out  = (float*)d_out;
    float* cost = out;                                   // [32]
    float* pi   = out + 32;                              // [32*512*512]
    float* C    = out + 32 + (size_t)NB * NN * NN;       // [32*512*512]

    // Workspace: flags + cp double buffer only.
    int* bars = (int*)d_ws;                                   // 8 KB
    float* cp0 = (float*)((char*)d_ws + 8192);                // 0.52 MB
    float* cp1 = cp0 + (size_t)NB * 8 * NN;                   // 0.52 MB

    gemm_cos_mfma<<<dim3(512), dim3(256), 0, stream>>>(
        x, y, C, cost, bars);

    const float* C_p = C;
    float* cp0_p = cp0; float* cp1_p = cp1;
    float* pi_p = pi; float* cost_p = cost; int* bars_p = bars;
    void* args[] = { &C_p, &cp0_p, &cp1_p, &pi_p, &cost_p, &bars_p };
    hipLaunchCooperativeKernel(reinterpret_cast<void*>(sink_fused),
                               dim3(256), dim3(512), args, 0, stream);
}